// Round 4
// baseline (292.158 us; speedup 1.0000x reference)
//
#include <hip/hip_runtime.h>
#include <hip/hip_fp16.h>
#include <math.h>

#define Bn 4
#define Cn 96
#define Hn 128
#define Wn 128
#define Ln (Hn*Wn)      // 16384
#define Kn 2
#define Rn 6
#define SC 16           // scan chunk length
#define NCH (Ln/SC)     // 1024 chunks per (b,k)

__device__ __forceinline__ float siluf(float x) { return x / (1.f + __expf(-x)); }
// native-instruction softplus: log1pf is a slow libm polynomial; __logf(1+e)
// is v_log_f32 with abs err < 1e-7 over our range (tolerance 2.5e-2).
__device__ __forceinline__ float softplusf(float x) {
    return fmaxf(x, 0.f) + __logf(1.f + __expf(-fabsf(x)));
}

// ---------------------------------------------------------------------------
// Kernel A: in_proj GEMM. x (B,C,L) -> xc (B,L,C), zs=silu(z) (B,L,C).
// ---------------------------------------------------------------------------
__global__ __launch_bounds__(256, 3) void k_inproj(
    const float* __restrict__ x, const float* __restrict__ ipw,
    float* __restrict__ xc, float* __restrict__ zs)
{
    __shared__ float smem[4096 + 6272];
    float* xls = smem;
    float* wls = smem + 4096;
    float* stage = smem;

    const int t  = threadIdx.x;
    const int b  = blockIdx.x >> 7;
    const int l0 = (blockIdx.x & 127) << 7;
    const int tx = t & 15;
    const int ty = t >> 4;

    float acc[12][8];
#pragma unroll
    for (int i = 0; i < 12; ++i)
#pragma unroll
        for (int j = 0; j < 8; ++j) acc[i][j] = 0.f;

    const float* xbase = x + (size_t)b * Cn * Ln + l0;

    for (int k0 = 0; k0 < Cn; k0 += 32) {
        if (k0) __syncthreads();
        {
            int idx = t;
#pragma unroll
            for (int q = 0; q < 4; ++q, idx += 256) {
                int k = idx >> 5, p4 = idx & 31;
                *(float4*)&xls[k * 128 + p4 * 4] =
                    *(const float4*)&xbase[(size_t)(k0 + k) * Ln + p4 * 4];
            }
        }
        for (int idx = t; idx < 32 * 192; idx += 256) {
            int o = idx % 192, k = idx / 192;
            wls[k * 196 + o] = ipw[o * Cn + k0 + k];
        }
        __syncthreads();

#pragma unroll 2
        for (int kk = 0; kk < 32; ++kk) {
            float4 xv0 = *(const float4*)&xls[kk * 128 + tx * 4];
            float4 xv1 = *(const float4*)&xls[kk * 128 + 64 + tx * 4];
            const float* wrow = &wls[kk * 196 + ty * 12];
            float4 w0 = *(const float4*)&wrow[0];
            float4 w1 = *(const float4*)&wrow[4];
            float4 w2 = *(const float4*)&wrow[8];
            float wv[12] = {w0.x,w0.y,w0.z,w0.w,w1.x,w1.y,w1.z,w1.w,w2.x,w2.y,w2.z,w2.w};
            float xa[8]  = {xv0.x,xv0.y,xv0.z,xv0.w,xv1.x,xv1.y,xv1.z,xv1.w};
#pragma unroll
            for (int i = 0; i < 12; ++i)
#pragma unroll
                for (int j = 0; j < 8; ++j)
                    acc[i][j] = fmaf(wv[i], xa[j], acc[i][j]);
        }
    }

    const size_t tilebase = (size_t)b * Ln + l0;
#pragma unroll
    for (int half_ = 0; half_ < 2; ++half_) {
        __syncthreads();
        if (ty < 8) {
#pragma unroll
            for (int j = 0; j < 4; ++j)
#pragma unroll
                for (int i = 0; i < 12; ++i)
                    stage[(tx * 4 + j) * 100 + ty * 12 + i] = acc[i][half_ * 4 + j];
        }
        __syncthreads();
        {
            float4* dst = (float4*)(xc + (tilebase + half_ * 64) * Cn);
            for (int idx = t; idx < 1536; idx += 256) {
                int p = idx / 24, c4 = idx % 24;
                dst[idx] = *(const float4*)&stage[p * 100 + c4 * 4];
            }
        }
        __syncthreads();
        if (ty >= 8) {
#pragma unroll
            for (int j = 0; j < 4; ++j)
#pragma unroll
                for (int i = 0; i < 12; ++i)
                    stage[(tx * 4 + j) * 100 + (ty - 8) * 12 + i] = siluf(acc[i][half_ * 4 + j]);
        }
        __syncthreads();
        {
            float4* dst = (float4*)(zs + (tilebase + half_ * 64) * Cn);
            for (int idx = t; idx < 1536; idx += 256) {
                int p = idx / 24, c4 = idx % 24;
                dst[idx] = *(const float4*)&stage[p * 100 + c4 * 4];
            }
        }
    }
}

// ---------------------------------------------------------------------------
// Kernel B: depthwise 3x3 conv (SAME) + bias + SiLU, float4 over channels.
// ---------------------------------------------------------------------------
__global__ __launch_bounds__(256) void k_conv(
    const float* __restrict__ xc, const float* __restrict__ cw,
    const float* __restrict__ cb, float* __restrict__ u)
{
    __shared__ float cws[9 * 96];   // [tap][c]
    for (int i = threadIdx.x; i < 864; i += 256) {
        int cc = i % 96, tap = i / 96;
        cws[tap * 96 + cc] = cw[cc * 9 + tap];
    }
    __syncthreads();

    const int e   = blockIdx.x * 256 + threadIdx.x;
    const int c4  = e % 24;
    const int pos = e / 24;
    const int l   = pos % Ln;
    const int b   = pos / Ln;
    const int h   = l >> 7, w = l & 127;
    const int c   = c4 * 4;

    float4 acc = *(const float4*)&cb[c];
#pragma unroll
    for (int dh = -1; dh <= 1; ++dh) {
        int hh = h + dh;
        if (hh < 0 || hh >= Hn) continue;
#pragma unroll
        for (int dw = -1; dw <= 1; ++dw) {
            int ww = w + dw;
            if (ww < 0 || ww >= Wn) continue;
            float4 wv = *(const float4*)&cws[((dh + 1) * 3 + (dw + 1)) * 96 + c];
            float4 xv = *(const float4*)&xc[((size_t)b * Ln + (hh << 7) + ww) * Cn + c];
            acc.x = fmaf(wv.x, xv.x, acc.x);
            acc.y = fmaf(wv.y, xv.y, acc.y);
            acc.z = fmaf(wv.z, xv.z, acc.z);
            acc.w = fmaf(wv.w, xv.w, acc.w);
        }
    }
    float4 r;
    r.x = siluf(acc.x); r.y = siluf(acc.y); r.z = siluf(acc.z); r.w = siluf(acc.w);
    *(float4*)&u[((size_t)b * Ln + l) * Cn + c] = r;
}

// ---------------------------------------------------------------------------
// Kernel C (k_part1, pipelined): each block owns 4 consecutive 32-pos tiles.
// R3 post-mortem: per-tile blocks were issue/latency-bound -- xpw re-read
// from global (24 float4 per dot), per-thread constants reloaded per block,
// u-load serialized by the first barrier.  Fixes here:
//   * xpw staged in LDS once per block (rows padded to 100 -> 2-way banks)
//   * dtw/dtb/Alogs/Ds hoisted out of the tile loop
//   * u tile t+1 prefetched into registers during tile t's GEMV+scan (T14)
// f = P*C (fp16) byte-overlays u per position (block-local, barrier-ordered);
// y0 = Q*C + (D0+D1)*u aliases dead xc.  Chunk/Pc/Qc layout unchanged.
// ---------------------------------------------------------------------------
__global__ __launch_bounds__(384, 3) void k_part1(
    const float* __restrict__ u, const float* __restrict__ xpw,
    const float* __restrict__ dtw, const float* __restrict__ dtb,
    const float* __restrict__ Alogs, const float* __restrict__ Ds,
    float* __restrict__ Pc, float* __restrict__ Qc,
    float* __restrict__ y0, __half* __restrict__ f)
{
    __shared__ float uls[32 * 100];  // u tile [p][c] pad 100
    __shared__ float yt [32 * 100];  // y merge buffer
    __shared__ float xd [32 * 16];   // x_dbl [p][dd]
    __shared__ float xw [16 * 100];  // xpw staged, row pad 100
    __shared__ float dsum[96];

    const int t  = threadIdx.x;
    const int jb = blockIdx.x & 127;
    const int b  = blockIdx.x >> 7;

    // stage xpw (16x96 -> padded rows) + dsum, once per block
    {
        int row = t / 24, c4 = t % 24;
        *(float4*)&xw[row * 100 + c4 * 4] = *(const float4*)&xpw[t * 4];
    }
    if (t < 96) dsum[t] = Ds[t] + Ds[Cn + t];

    // per-thread scan constants, hoisted
    const int c  = t % 96;
    const int ci = (t / 96) & 1;     // chunk within tile: 0..1
    const int k  = t / 192;
    const int bk = b * Kn + k;
    const float Av   = -__expf(Alogs[k * Cn + c]);
    const float bias = dtb[k * Cn + c];
    float dtwr[Rn];
#pragma unroll
    for (int r = 0; r < Rn; ++r) dtwr[r] = dtw[(k * Cn + c) * Rn + r];

    const int   p0  = t / 24, c40 = t % 24;         // staging lanes
    const float* utile = u + ((size_t)b * Ln + (size_t)jb * 128) * Cn;

    // prefetch tile 0
    float4 nx0 = *(const float4*)&utile[t * 4];
    float4 nx1 = *(const float4*)&utile[(t + 384) * 4];

#pragma unroll 1
    for (int tt = 0; tt < 4; ++tt) {
        const int j  = jb * 4 + tt;
        const int l0 = j << 5;

        // commit prefetched u tile to LDS (prev readers done at last barrier)
        *(float4*)&uls[p0 * 100 + c40 * 4]        = nx0;
        *(float4*)&uls[(p0 + 16) * 100 + c40 * 4] = nx1;
        // issue next tile's loads -- they fly during GEMV + scan
        if (tt < 3) {
            const float* un = utile + (size_t)(tt + 1) * 3072;
            nx0 = *(const float4*)&un[t * 4];
            nx1 = *(const float4*)&un[(t + 384) * 4];
        }
        __syncthreads();   // uls + (tt==0) xw/dsum ready

        // x_dbl: 16 projections x 32 positions, both operands in LDS
        for (int dp = t; dp < 512; dp += 384) {
            int dd = dp & 15, p = dp >> 4;
            const float4* wr = (const float4*)&xw[dd * 100];
            const float4* ur = (const float4*)&uls[p * 100];
            float acc = 0.f;
#pragma unroll
            for (int c4 = 0; c4 < 24; ++c4) {
                float4 w = wr[c4], v = ur[c4];
                acc = fmaf(w.x, v.x, acc); acc = fmaf(w.y, v.y, acc);
                acc = fmaf(w.z, v.z, acc); acc = fmaf(w.w, v.w, acc);
            }
            xd[p * 16 + dd] = acc;
        }
        __syncthreads();   // xd ready

        // chunk scans: k=0 chunk 2j+ci, p = ci*16+i ascending
        //              k=1 chunk 1022-2j+ci, p = (1-ci)*16+(15-i)
        const int chunk = (k == 0) ? (2 * j + ci) : (1022 - 2 * j + ci);
        const int xoff = k * 8;
        __half* fkc = f + ((size_t)(b * Ln + l0) * 2 + k) * Cn + c;
        const float dsc = dsum[c];

        float h = 0.f, cp = 1.f;
        float yreg[SC];
#pragma unroll
        for (int hf = 0; hf < 2; ++hf) {
            float dAv[8], dBu[8], Cl[8], uv[8];
#pragma unroll
            for (int i = 0; i < 8; ++i) {
                const int ii = hf * 8 + i;
                const int p = (k == 0) ? (ci * 16 + ii) : ((1 - ci) * 16 + (15 - ii));
                const float* xr = &xd[p * 16 + xoff];
                float de = bias;
#pragma unroll
                for (int r = 0; r < Rn; ++r) de = fmaf(dtwr[r], xr[r], de);
                de = softplusf(de);
                uv[i]  = uls[p * 100 + c];
                dAv[i] = __expf(de * Av);
                dBu[i] = de * uv[i] * xr[6];
                Cl[i]  = xr[7];
            }
#pragma unroll
            for (int i = 0; i < 8; ++i) {
                const int ii = hf * 8 + i;
                const int p = (k == 0) ? (ci * 16 + ii) : ((1 - ci) * 16 + (15 - ii));
                h  = fmaf(dAv[i], h, dBu[i]);
                cp *= dAv[i];
                yreg[ii] = (k == 0) ? fmaf(dsc, uv[i], h * Cl[i]) : (h * Cl[i]);
                fkc[(size_t)p * (2 * Cn)] = __float2half(cp * Cl[i]);
            }
        }
        {
            const size_t cidx = ((size_t)bk * NCH + chunk) * Cn + c;
            Pc[cidx] = cp;
            Qc[cidx] = h;
        }

        // merge y0 across directions through yt
        if (k == 0) {
#pragma unroll
            for (int i = 0; i < SC; ++i)
                yt[(ci * 16 + i) * 100 + c] = yreg[i];
        }
        __syncthreads();   // k0 part written (also: all uls/xd reads done)
        if (k == 1) {
#pragma unroll
            for (int i = 0; i < SC; ++i)
                yt[((1 - ci) * 16 + (15 - i)) * 100 + c] += yreg[i];
        }
        __syncthreads();   // yt complete
        {
            float4* y4 = (float4*)(y0 + ((size_t)b * Ln + l0) * Cn);
            y4[t]       = *(const float4*)&yt[p0 * 100 + c40 * 4];
            y4[t + 384] = *(const float4*)&yt[(p0 + 16) * 100 + c40 * 4];
        }
        // loop back: uls overwrite is safe (all uls reads were pre-B3);
        // yt rewrite waits for next iter's B2.
    }
}

// ---------------------------------------------------------------------------
// Kernel D: hierarchical carry scan (unchanged). 768 series x 1024 chunks.
// ---------------------------------------------------------------------------
__global__ __launch_bounds__(1024) void k_scan2(
    const float* __restrict__ Pc, const float* __restrict__ Qc,
    float* __restrict__ hinit)
{
    __shared__ float Pg[32][33], Qg[32][33], gini[32][33];
    const int bk    = blockIdx.x / 3;
    const int cbase = (blockIdx.x % 3) * 32;
    const int t = threadIdx.x;
    const int c = t & 31, g = t >> 5;

    const size_t base = ((size_t)bk * NCH + g * 32) * Cn + cbase + c;
    float P = 1.f, Q = 0.f;
    for (int j = 0; j < 32; ++j) {
        size_t idx = base + (size_t)j * Cn;
        float p_ = Pc[idx], q_ = Qc[idx];
        Q = fmaf(p_, Q, q_);
        P *= p_;
    }
    Pg[g][c] = P; Qg[g][c] = Q;
    __syncthreads();
    if (t < 32) {
        float h = 0.f;
        for (int gg = 0; gg < 32; ++gg) {
            gini[gg][t] = h;
            h = fmaf(Pg[gg][t], h, Qg[gg][t]);
        }
    }
    __syncthreads();
    float h = gini[g][c];
    for (int j = 0; j < 32; ++j) {
        size_t idx = base + (size_t)j * Cn;
        hinit[idx] = h;
        h = fmaf(Pc[idx], h, Qc[idx]);
    }
}

// ---------------------------------------------------------------------------
// Kernel E (k_merge): streaming merge + LN + gate + fused out_proj GEMM.
//   y = y0 + hinit0*f0 + hinit1*f1 ; LN ; *silu(z) ; out = opw @ g * scw
// ---------------------------------------------------------------------------
__global__ __launch_bounds__(512) void k_merge(
    const float* __restrict__ y0, const __half* __restrict__ f,
    const float* __restrict__ hinit, const float* __restrict__ zs,
    const float* __restrict__ onw, const float* __restrict__ onb,
    const float* __restrict__ opw, const float* __restrict__ scw,
    float* __restrict__ out)
{
    __shared__ float gt[64 * 104];   // y -> gated g -> reused as outT[o][68]
    __shared__ float wls[96 * 36];   // opw chunk [o][32] pad 36
    __shared__ float h0s[4 * 96], h1s[4 * 96];
    __shared__ float mu[64], isd[64];
    const int t  = threadIdx.x;
    const int j  = blockIdx.x & 255;
    const int b  = blockIdx.x >> 8;
    const int l0 = j << 6;

    for (int idx = t; idx < 768; idx += 512) {
        if (idx < 384) {
            int q = idx / 96, c = idx % 96;
            h0s[q * 96 + c] = hinit[((size_t)(b * 2 + 0) * NCH + 4 * j + q) * Cn + c];
        } else {
            int i2 = idx - 384;
            int q = i2 / 96, c = i2 % 96;
            h1s[q * 96 + c] = hinit[((size_t)(b * 2 + 1) * NCH + (1023 - 4 * j - q)) * Cn + c];
        }
    }
    __syncthreads();

    // elementwise merge: y = y0 + h0*f0 + h1*f1  -> gt[p][c]
    {
        const float4* y4 = (const float4*)(y0 + ((size_t)b * Ln + l0) * Cn);
        const __half* fb = f + (size_t)(b * Ln + l0) * 2 * Cn;
        for (int e4 = t; e4 < 1536; e4 += 512) {
            int p = e4 / 24, c4 = e4 % 24;
            float4 yv = y4[e4];
            const __half* fp0 = fb + (size_t)p * (2 * Cn) + c4 * 4;
            const __half2* f0h = (const __half2*)fp0;
            const __half2* f1h = (const __half2*)(fp0 + Cn);
            float2 fa0 = __half22float2(f0h[0]);
            float2 fa1 = __half22float2(f0h[1]);
            float2 fb0 = __half22float2(f1h[0]);
            float2 fb1 = __half22float2(f1h[1]);
            const float4 h0v = *(const float4*)&h0s[(p >> 4) * 96 + c4 * 4];
            const float4 h1v = *(const float4*)&h1s[(p >> 4) * 96 + c4 * 4];
            yv.x = fmaf(h0v.x, fa0.x, fmaf(h1v.x, fb0.x, yv.x));
            yv.y = fmaf(h0v.y, fa0.y, fmaf(h1v.y, fb0.y, yv.y));
            yv.z = fmaf(h0v.z, fa1.x, fmaf(h1v.z, fb1.x, yv.z));
            yv.w = fmaf(h0v.w, fa1.y, fmaf(h1v.w, fb1.y, yv.w));
            *(float4*)&gt[p * 104 + c4 * 4] = yv;
        }
    }
    __syncthreads();

    if (t < 256) {
        const int p = t >> 2, q = t & 3;
        const float4* row = (const float4*)&gt[p * 104 + q * 24];
        float s = 0.f, ss = 0.f;
#pragma unroll
        for (int i = 0; i < 6; ++i) {
            float4 v = row[i];
            s  += v.x + v.y + v.z + v.w;
            ss += v.x*v.x + v.y*v.y + v.z*v.z + v.w*v.w;
        }
        s  += __shfl_xor(s, 1);  s  += __shfl_xor(s, 2);
        ss += __shfl_xor(ss, 1); ss += __shfl_xor(ss, 2);
        if (q == 0) {
            float m = s * (1.f / Cn);
            mu[p] = m;
            isd[p] = rsqrtf(ss * (1.f / Cn) - m * m + 1e-5f);
        }
    }
    __syncthreads();

    {
        const float4* zp4 = (const float4*)(zs + ((size_t)b * Ln + l0) * Cn);
        const float4* w4  = (const float4*)onw;
        const float4* b4  = (const float4*)onb;
        for (int e4 = t; e4 < 1536; e4 += 512) {
            int p = e4 / 24, c4 = e4 % 24;
            float4 v = *(const float4*)&gt[p * 104 + c4 * 4];
            float4 wv = w4[c4], bv = b4[c4], zv = zp4[e4];
            float m = mu[p], is = isd[p];
            v.x = ((v.x - m) * is * wv.x + bv.x) * zv.x;
            v.y = ((v.y - m) * is * wv.y + bv.y) * zv.y;
            v.z = ((v.z - m) * is * wv.z + bv.z) * zv.z;
            v.w = ((v.w - m) * is * wv.w + bv.w) * zv.w;
            *(float4*)&gt[p * 104 + c4 * 4] = v;
        }
    }

    const int og = t & 31, pg = t >> 5;
    float acc[3][4];
#pragma unroll
    for (int i = 0; i < 3; ++i)
#pragma unroll
        for (int r = 0; r < 4; ++r) acc[i][r] = 0.f;

    for (int k0 = 0; k0 < Cn; k0 += 32) {
        __syncthreads();
        for (int e4 = t; e4 < 768; e4 += 512) {
            int o = e4 >> 3, c4 = e4 & 7;
            *(float4*)&wls[o * 36 + c4 * 4] = *(const float4*)&opw[o * Cn + k0 + c4 * 4];
        }
        __syncthreads();
#pragma unroll
        for (int c4 = 0; c4 < 8; ++c4) {
            float4 w0 = *(const float4*)&wls[(og * 3 + 0) * 36 + c4 * 4];
            float4 w1 = *(const float4*)&wls[(og * 3 + 1) * 36 + c4 * 4];
            float4 w2 = *(const float4*)&wls[(og * 3 + 2) * 36 + c4 * 4];
            float4 g0 = *(const float4*)&gt[(pg * 4 + 0) * 104 + k0 + c4 * 4];
            float4 g1 = *(const float4*)&gt[(pg * 4 + 1) * 104 + k0 + c4 * 4];
            float4 g2 = *(const float4*)&gt[(pg * 4 + 2) * 104 + k0 + c4 * 4];
            float4 g3 = *(const float4*)&gt[(pg * 4 + 3) * 104 + k0 + c4 * 4];
#define ACC1(i, wv, r, gv) \
            acc[i][r] = fmaf(wv.x, gv.x, acc[i][r]); \
            acc[i][r] = fmaf(wv.y, gv.y, acc[i][r]); \
            acc[i][r] = fmaf(wv.z, gv.z, acc[i][r]); \
            acc[i][r] = fmaf(wv.w, gv.w, acc[i][r]);
            ACC1(0, w0, 0, g0) ACC1(0, w0, 1, g1) ACC1(0, w0, 2, g2) ACC1(0, w0, 3, g3)
            ACC1(1, w1, 0, g0) ACC1(1, w1, 1, g1) ACC1(1, w1, 2, g2) ACC1(1, w1, 3, g3)
            ACC1(2, w2, 0, g0) ACC1(2, w2, 1, g1) ACC1(2, w2, 2, g2) ACC1(2, w2, 3, g3)
#undef ACC1
        }
    }

    __syncthreads();
#pragma unroll
    for (int i = 0; i < 3; ++i)
#pragma unroll
        for (int r = 0; r < 4; ++r)
            gt[(og * 3 + i) * 68 + pg * 4 + r] = acc[i][r];
    __syncthreads();

    {
        float* ob = out + (size_t)b * Cn * Ln + l0;
        for (int e4 = t; e4 < 1536; e4 += 512) {
            int o = e4 >> 4, p4 = e4 & 15;
            float4 v = *(const float4*)&gt[o * 68 + p4 * 4];
            float sc = scw[o];
            v.x *= sc; v.y *= sc; v.z *= sc; v.w *= sc;
            *(float4*)&ob[(size_t)o * Ln + p4 * 4] = v;
        }
    }
}

// ---------------------------------------------------------------------------
extern "C" void kernel_launch(void* const* d_in, const int* in_sizes, int n_in,
                              void* d_out, int out_size, void* d_ws, size_t ws_size,
                              hipStream_t stream)
{
    const float* x     = (const float*)d_in[0];
    const float* ipw   = (const float*)d_in[1];
    const float* cw    = (const float*)d_in[2];
    const float* cb    = (const float*)d_in[3];
    const float* xpw   = (const float*)d_in[4];
    const float* dtw   = (const float*)d_in[5];
    const float* dtb   = (const float*)d_in[6];
    const float* Alogs = (const float*)d_in[7];
    const float* Ds    = (const float*)d_in[8];
    const float* onw   = (const float*)d_in[9];
    const float* onb   = (const float*)d_in[10];
    const float* opw   = (const float*)d_in[11];
    const float* scw   = (const float*)d_in[12];
    float* out = (float*)d_out;

    float* wsp = (float*)d_ws;
    size_t off = 0;
    // xc dead after k_conv -> y0 aliases it
    float* xc   = wsp + off;
    float* y0   = wsp + off; off += (size_t)Bn * Ln * Cn;         // 6.29M
    float* zs   = wsp + off; off += (size_t)Bn * Ln * Cn;         // 6.29M
    float* u    = wsp + off; off += (size_t)Bn * Ln * Cn;         // 6.29M
    // f (fp16, [b][l][k][c]) overlays u byte-exactly per position; each part1
    // block consumes its own u range (LDS or prefetch regs) before overwriting.
    __half* f   = (__half*)u;
    float* Pc    = wsp + off; off += (size_t)Bn * Kn * NCH * Cn;  // 0.79M
    float* Qc    = wsp + off; off += (size_t)Bn * Kn * NCH * Cn;
    float* hinit = wsp + off; off += (size_t)Bn * Kn * NCH * Cn;

    k_inproj<<<Bn * 128, 256, 0, stream>>>(x, ipw, xc, zs);
    k_conv  <<<(Bn * Ln * 24) / 256, 256, 0, stream>>>(xc, cw, cb, u);
    k_part1 <<<Bn * 128, 384, 0, stream>>>(u, xpw, dtw, dtb, Alogs, Ds,
                                           Pc, Qc, y0, f);
    k_scan2 <<<24, 1024, 0, stream>>>(Pc, Qc, hinit);
    k_merge <<<Bn * 256, 512, 0, stream>>>(y0, f, hinit, zs, onw, onb,
                                           opw, scw, out);
}

// Round 5
// 266.465 us; speedup vs baseline: 1.0964x; 1.0964x over previous
//
#include <hip/hip_runtime.h>
#include <hip/hip_fp16.h>
#include <math.h>

#define Bn 4
#define Cn 96
#define Hn 128
#define Wn 128
#define Ln (Hn*Wn)      // 16384
#define Kn 2
#define Rn 6
#define SC 16           // scan chunk length
#define NCH (Ln/SC)     // 1024 chunks per (b,k)

__device__ __forceinline__ float siluf(float x) { return x / (1.f + __expf(-x)); }
// native-instruction softplus: log1pf is a slow libm polynomial; __logf(1+e)
// is v_log_f32 with abs err < 1e-7 over our range (tolerance 2.5e-2).
__device__ __forceinline__ float softplusf(float x) {
    return fmaxf(x, 0.f) + __logf(1.f + __expf(-fabsf(x)));
}

__device__ __forceinline__ ushort4 pack4h(float4 v) {
    ushort4 r;
    r.x = __half_as_ushort(__float2half(v.x));
    r.y = __half_as_ushort(__float2half(v.y));
    r.z = __half_as_ushort(__float2half(v.z));
    r.w = __half_as_ushort(__float2half(v.w));
    return r;
}
__device__ __forceinline__ float4 unpack4h(const __half* p) {
    const __half2* h2 = (const __half2*)p;
    float2 a = __half22float2(h2[0]);
    float2 b = __half22float2(h2[1]);
    return make_float4(a.x, a.y, b.x, b.y);
}

// ---------------------------------------------------------------------------
// Kernel A: in_proj GEMM. x (B,C,L) -> xc (B,L,C) fp32, zs=silu(z) fp16.
// ---------------------------------------------------------------------------
__global__ __launch_bounds__(256, 3) void k_inproj(
    const float* __restrict__ x, const float* __restrict__ ipw,
    float* __restrict__ xc, __half* __restrict__ zs)
{
    __shared__ float smem[4096 + 6272];
    float* xls = smem;
    float* wls = smem + 4096;
    float* stage = smem;

    const int t  = threadIdx.x;
    const int b  = blockIdx.x >> 7;
    const int l0 = (blockIdx.x & 127) << 7;
    const int tx = t & 15;
    const int ty = t >> 4;

    float acc[12][8];
#pragma unroll
    for (int i = 0; i < 12; ++i)
#pragma unroll
        for (int j = 0; j < 8; ++j) acc[i][j] = 0.f;

    const float* xbase = x + (size_t)b * Cn * Ln + l0;

    for (int k0 = 0; k0 < Cn; k0 += 32) {
        if (k0) __syncthreads();
        {
            int idx = t;
#pragma unroll
            for (int q = 0; q < 4; ++q, idx += 256) {
                int k = idx >> 5, p4 = idx & 31;
                *(float4*)&xls[k * 128 + p4 * 4] =
                    *(const float4*)&xbase[(size_t)(k0 + k) * Ln + p4 * 4];
            }
        }
        for (int idx = t; idx < 32 * 192; idx += 256) {
            int o = idx % 192, k = idx / 192;
            wls[k * 196 + o] = ipw[o * Cn + k0 + k];
        }
        __syncthreads();

#pragma unroll 2
        for (int kk = 0; kk < 32; ++kk) {
            float4 xv0 = *(const float4*)&xls[kk * 128 + tx * 4];
            float4 xv1 = *(const float4*)&xls[kk * 128 + 64 + tx * 4];
            const float* wrow = &wls[kk * 196 + ty * 12];
            float4 w0 = *(const float4*)&wrow[0];
            float4 w1 = *(const float4*)&wrow[4];
            float4 w2 = *(const float4*)&wrow[8];
            float wv[12] = {w0.x,w0.y,w0.z,w0.w,w1.x,w1.y,w1.z,w1.w,w2.x,w2.y,w2.z,w2.w};
            float xa[8]  = {xv0.x,xv0.y,xv0.z,xv0.w,xv1.x,xv1.y,xv1.z,xv1.w};
#pragma unroll
            for (int i = 0; i < 12; ++i)
#pragma unroll
                for (int j = 0; j < 8; ++j)
                    acc[i][j] = fmaf(wv[i], xa[j], acc[i][j]);
        }
    }

    const size_t tilebase = (size_t)b * Ln + l0;
#pragma unroll
    for (int half_ = 0; half_ < 2; ++half_) {
        __syncthreads();
        if (ty < 8) {
#pragma unroll
            for (int j = 0; j < 4; ++j)
#pragma unroll
                for (int i = 0; i < 12; ++i)
                    stage[(tx * 4 + j) * 100 + ty * 12 + i] = acc[i][half_ * 4 + j];
        }
        __syncthreads();
        {
            float4* dst = (float4*)(xc + (tilebase + half_ * 64) * Cn);
            for (int idx = t; idx < 1536; idx += 256) {
                int p = idx / 24, c4 = idx % 24;
                dst[idx] = *(const float4*)&stage[p * 100 + c4 * 4];
            }
        }
        __syncthreads();
        if (ty >= 8) {
#pragma unroll
            for (int j = 0; j < 4; ++j)
#pragma unroll
                for (int i = 0; i < 12; ++i)
                    stage[(tx * 4 + j) * 100 + (ty - 8) * 12 + i] = siluf(acc[i][half_ * 4 + j]);
        }
        __syncthreads();
        {
            __half* dst = zs + (tilebase + half_ * 64) * Cn;
            for (int idx = t; idx < 1536; idx += 256) {
                int p = idx / 24, c4 = idx % 24;
                float4 v = *(const float4*)&stage[p * 100 + c4 * 4];
                *(ushort4*)(dst + (size_t)p * Cn + c4 * 4) = pack4h(v);
            }
        }
    }
}

// ---------------------------------------------------------------------------
// Kernel C (k_part1 + fused depthwise conv): R3's proven per-32-pos-tile
// structure, but fed directly from xc.  Each block stages the 3x34 xc halo,
// computes conv+SiLU into uls during its latency slack (conv ~50 fma/thread,
// free in a latency-bound kernel), then runs the unchanged GEMV/scan/merge.
// Kills k_conv and the 50 MB u round-trip; halo re-reads are L2-served.
// f has its own buffer now (no u-overlay aliasing).  y0 stored fp16.
// No launch_bounds min-waves, no reg prefetch (R2/R4 spill post-mortems).
// ---------------------------------------------------------------------------
__global__ __launch_bounds__(384) void k_part1(
    const float* __restrict__ xc, const float* __restrict__ cw,
    const float* __restrict__ cb, const float* __restrict__ xpw,
    const float* __restrict__ dtw, const float* __restrict__ dtb,
    const float* __restrict__ Alogs, const float* __restrict__ Ds,
    float* __restrict__ Pc, float* __restrict__ Qc,
    __half* __restrict__ y0, __half* __restrict__ f)
{
    __shared__ float xcl[3 * 34 * 96];   // 38.3 KB halo [r][wcol][c]; dead after conv
    __shared__ float uls[32 * 100];      // u tile [p][c]
    __shared__ float xd [32 * 16];       // x_dbl [p][dd]
    __shared__ float cws[9 * 96];        // conv weights [tap][c]
    __shared__ float dsum[96];
    float* yt = xcl + 4800;              // 32x96 merge buffer (aliases dead xcl)

    const int t  = threadIdx.x;
    const int j  = blockIdx.x & 511;
    const int b  = blockIdx.x >> 9;
    const int h  = j >> 2;
    const int w0 = (j & 3) << 5;
    const int l0 = j << 5;               // = h*128 + w0

    // ---- stage xc halo (zero-padded SAME) + conv weights + dsum ----
    {
        const float* xb = xc + (size_t)b * Ln * Cn;
        for (int idx = t; idx < 3 * 34 * 24; idx += 384) {
            int r = idx / (34 * 24), rem = idx % (34 * 24);
            int wc = rem / 24, c4 = rem % 24;
            int hh = h - 1 + r, ww = w0 - 1 + wc;
            float4 v = make_float4(0.f, 0.f, 0.f, 0.f);
            if (hh >= 0 && hh < Hn && ww >= 0 && ww < Wn)
                v = *(const float4*)&xb[((size_t)(hh << 7) + ww) * Cn + c4 * 4];
            *(float4*)&xcl[(r * 34 + wc) * 96 + c4 * 4] = v;
        }
        for (int i = t; i < 864; i += 384) {
            int cc = i % 96, tap = i / 96;
            cws[tap * 96 + cc] = cw[cc * 9 + tap];
        }
        if (t < 96) dsum[t] = Ds[t] + Ds[Cn + t];
    }
    __syncthreads();

    // ---- depthwise 3x3 conv + bias + SiLU -> uls ----
    for (int idx = t; idx < 768; idx += 384) {
        int p = idx / 24, c4 = idx % 24;
        float4 acc = *(const float4*)&cb[c4 * 4];
#pragma unroll
        for (int r = 0; r < 3; ++r)
#pragma unroll
            for (int dw = 0; dw < 3; ++dw) {
                float4 wv = *(const float4*)&cws[(r * 3 + dw) * 96 + c4 * 4];
                float4 xv = *(const float4*)&xcl[(r * 34 + p + dw) * 96 + c4 * 4];
                acc.x = fmaf(wv.x, xv.x, acc.x);
                acc.y = fmaf(wv.y, xv.y, acc.y);
                acc.z = fmaf(wv.z, xv.z, acc.z);
                acc.w = fmaf(wv.w, xv.w, acc.w);
            }
        float4 rr;
        rr.x = siluf(acc.x); rr.y = siluf(acc.y);
        rr.z = siluf(acc.z); rr.w = siluf(acc.w);
        *(float4*)&uls[p * 100 + c4 * 4] = rr;
    }
    __syncthreads();

    // ---- x_dbl GEMV: 16 projections x 32 positions (xpw from L2) ----
    for (int dp = t; dp < 512; dp += 384) {
        int dd = dp & 15, p = dp >> 4;
        const float4* wr = (const float4*)(xpw + dd * Cn);
        const float4* ur = (const float4*)&uls[p * 100];
        float acc = 0.f;
#pragma unroll
        for (int c4 = 0; c4 < 24; ++c4) {
            float4 w = wr[c4], v = ur[c4];
            acc = fmaf(w.x, v.x, acc); acc = fmaf(w.y, v.y, acc);
            acc = fmaf(w.z, v.z, acc); acc = fmaf(w.w, v.w, acc);
        }
        xd[p * 16 + dd] = acc;
    }
    __syncthreads();

    // ---- chunk scans (unchanged R3 math) ----
    const int c  = t % 96;
    const int ci = (t / 96) & 1;     // chunk within tile: 0..1
    const int k  = t / 192;
    const int bk = b * Kn + k;
    const float Av   = -__expf(Alogs[k * Cn + c]);
    const float bias = dtb[k * Cn + c];
    const float dsc  = dsum[c];
    float dtwr[Rn];
#pragma unroll
    for (int r = 0; r < Rn; ++r) dtwr[r] = dtw[(k * Cn + c) * Rn + r];

    // k=0: chunk 2j+ci covers spatial p = ci*16 + i (i ascending)
    // k=1: chunk 1022-2j+ci covers spatial p = (1-ci)*16 + (15-i)
    const int chunk = (k == 0) ? (2 * j + ci) : (1022 - 2 * j + ci);
    const int xoff = k * 8;
    __half* fkc = f + ((size_t)(b * Ln + l0) * 2 + k) * Cn + c;

    float h_ = 0.f, cp = 1.f;
    float yreg[SC];
#pragma unroll
    for (int hf = 0; hf < 2; ++hf) {
        float dAv[8], dBu[8], Cl[8], uv[8];
#pragma unroll
        for (int i = 0; i < 8; ++i) {
            const int ii = hf * 8 + i;
            const int p = (k == 0) ? (ci * 16 + ii) : ((1 - ci) * 16 + (15 - ii));
            const float* xr = &xd[p * 16 + xoff];
            float de = bias;
#pragma unroll
            for (int r = 0; r < Rn; ++r) de = fmaf(dtwr[r], xr[r], de);
            de = softplusf(de);
            uv[i]  = uls[p * 100 + c];
            dAv[i] = __expf(de * Av);
            dBu[i] = de * uv[i] * xr[6];
            Cl[i]  = xr[7];
        }
#pragma unroll
        for (int i = 0; i < 8; ++i) {
            const int ii = hf * 8 + i;
            const int p = (k == 0) ? (ci * 16 + ii) : ((1 - ci) * 16 + (15 - ii));
            h_  = fmaf(dAv[i], h_, dBu[i]);
            cp *= dAv[i];
            yreg[ii] = (k == 0) ? fmaf(dsc, uv[i], h_ * Cl[i]) : (h_ * Cl[i]);
            fkc[(size_t)p * (2 * Cn)] = __float2half(cp * Cl[i]);
        }
    }
    {
        const size_t cidx = ((size_t)bk * NCH + chunk) * Cn + c;
        Pc[cidx] = cp;
        Qc[cidx] = h_;
    }

    // ---- merge directions through yt (aliases dead xcl), store y0 fp16 ----
    if (k == 0) {
#pragma unroll
        for (int i = 0; i < SC; ++i)
            yt[(ci * 16 + i) * 96 + c] = yreg[i];
    }
    __syncthreads();   // k0 writes visible
    if (k == 1) {
#pragma unroll
        for (int i = 0; i < SC; ++i)
            yt[((1 - ci) * 16 + (15 - i)) * 96 + c] += yreg[i];
    }
    __syncthreads();   // yt complete
    {
        const int p0 = t / 24, c40 = t % 24;
        __half* yb = y0 + ((size_t)b * Ln + l0) * Cn;
        float4 v0 = *(const float4*)&yt[p0 * 96 + c40 * 4];
        float4 v1 = *(const float4*)&yt[(p0 + 16) * 96 + c40 * 4];
        *(ushort4*)(yb + (size_t)p0 * Cn + c40 * 4)        = pack4h(v0);
        *(ushort4*)(yb + (size_t)(p0 + 16) * Cn + c40 * 4) = pack4h(v1);
    }
}

// ---------------------------------------------------------------------------
// Kernel D: hierarchical carry scan (unchanged). 768 series x 1024 chunks.
// ---------------------------------------------------------------------------
__global__ __launch_bounds__(1024) void k_scan2(
    const float* __restrict__ Pc, const float* __restrict__ Qc,
    float* __restrict__ hinit)
{
    __shared__ float Pg[32][33], Qg[32][33], gini[32][33];
    const int bk    = blockIdx.x / 3;
    const int cbase = (blockIdx.x % 3) * 32;
    const int t = threadIdx.x;
    const int c = t & 31, g = t >> 5;

    const size_t base = ((size_t)bk * NCH + g * 32) * Cn + cbase + c;
    float P = 1.f, Q = 0.f;
    for (int j = 0; j < 32; ++j) {
        size_t idx = base + (size_t)j * Cn;
        float p_ = Pc[idx], q_ = Qc[idx];
        Q = fmaf(p_, Q, q_);
        P *= p_;
    }
    Pg[g][c] = P; Qg[g][c] = Q;
    __syncthreads();
    if (t < 32) {
        float h = 0.f;
        for (int gg = 0; gg < 32; ++gg) {
            gini[gg][t] = h;
            h = fmaf(Pg[gg][t], h, Qg[gg][t]);
        }
    }
    __syncthreads();
    float h = gini[g][c];
    for (int j = 0; j < 32; ++j) {
        size_t idx = base + (size_t)j * Cn;
        hinit[idx] = h;
        h = fmaf(Pc[idx], h, Qc[idx]);
    }
}

// ---------------------------------------------------------------------------
// Kernel E (k_merge): streaming merge + LN + gate + fused out_proj GEMM.
//   y = y0 + hinit0*f0 + hinit1*f1 ; LN ; *silu(z) ; out = opw @ g * scw
// y0 and zs are fp16 streams now.
// ---------------------------------------------------------------------------
__global__ __launch_bounds__(512) void k_merge(
    const __half* __restrict__ y0, const __half* __restrict__ f,
    const float* __restrict__ hinit, const __half* __restrict__ zs,
    const float* __restrict__ onw, const float* __restrict__ onb,
    const float* __restrict__ opw, const float* __restrict__ scw,
    float* __restrict__ out)
{
    __shared__ float gt[64 * 104];   // y -> gated g -> reused as outT[o][68]
    __shared__ float wls[96 * 36];   // opw chunk [o][32] pad 36
    __shared__ float h0s[4 * 96], h1s[4 * 96];
    __shared__ float mu[64], isd[64];
    const int t  = threadIdx.x;
    const int j  = blockIdx.x & 255;
    const int b  = blockIdx.x >> 8;
    const int l0 = j << 6;

    for (int idx = t; idx < 768; idx += 512) {
        if (idx < 384) {
            int q = idx / 96, c = idx % 96;
            h0s[q * 96 + c] = hinit[((size_t)(b * 2 + 0) * NCH + 4 * j + q) * Cn + c];
        } else {
            int i2 = idx - 384;
            int q = i2 / 96, c = i2 % 96;
            h1s[q * 96 + c] = hinit[((size_t)(b * 2 + 1) * NCH + (1023 - 4 * j - q)) * Cn + c];
        }
    }
    __syncthreads();

    // elementwise merge: y = y0 + h0*f0 + h1*f1  -> gt[p][c]
    {
        const __half* yb = y0 + ((size_t)b * Ln + l0) * Cn;
        const __half* fb = f + (size_t)(b * Ln + l0) * 2 * Cn;
        for (int e4 = t; e4 < 1536; e4 += 512) {
            int p = e4 / 24, c4 = e4 % 24;
            float4 yv = unpack4h(yb + (size_t)p * Cn + c4 * 4);
            const __half* fp0 = fb + (size_t)p * (2 * Cn) + c4 * 4;
            float4 f0 = unpack4h(fp0);
            float4 f1 = unpack4h(fp0 + Cn);
            const float4 h0v = *(const float4*)&h0s[(p >> 4) * 96 + c4 * 4];
            const float4 h1v = *(const float4*)&h1s[(p >> 4) * 96 + c4 * 4];
            yv.x = fmaf(h0v.x, f0.x, fmaf(h1v.x, f1.x, yv.x));
            yv.y = fmaf(h0v.y, f0.y, fmaf(h1v.y, f1.y, yv.y));
            yv.z = fmaf(h0v.z, f0.z, fmaf(h1v.z, f1.z, yv.z));
            yv.w = fmaf(h0v.w, f0.w, fmaf(h1v.w, f1.w, yv.w));
            *(float4*)&gt[p * 104 + c4 * 4] = yv;
        }
    }
    __syncthreads();

    if (t < 256) {
        const int p = t >> 2, q = t & 3;
        const float4* row = (const float4*)&gt[p * 104 + q * 24];
        float s = 0.f, ss = 0.f;
#pragma unroll
        for (int i = 0; i < 6; ++i) {
            float4 v = row[i];
            s  += v.x + v.y + v.z + v.w;
            ss += v.x*v.x + v.y*v.y + v.z*v.z + v.w*v.w;
        }
        s  += __shfl_xor(s, 1);  s  += __shfl_xor(s, 2);
        ss += __shfl_xor(ss, 1); ss += __shfl_xor(ss, 2);
        if (q == 0) {
            float m = s * (1.f / Cn);
            mu[p] = m;
            isd[p] = rsqrtf(ss * (1.f / Cn) - m * m + 1e-5f);
        }
    }
    __syncthreads();

    {
        const __half* zb = zs + ((size_t)b * Ln + l0) * Cn;
        const float4* w4  = (const float4*)onw;
        const float4* b4  = (const float4*)onb;
        for (int e4 = t; e4 < 1536; e4 += 512) {
            int p = e4 / 24, c4 = e4 % 24;
            float4 v = *(const float4*)&gt[p * 104 + c4 * 4];
            float4 wv = w4[c4], bv = b4[c4];
            float4 zv = unpack4h(zb + (size_t)p * Cn + c4 * 4);
            float m = mu[p], is = isd[p];
            v.x = ((v.x - m) * is * wv.x + bv.x) * zv.x;
            v.y = ((v.y - m) * is * wv.y + bv.y) * zv.y;
            v.z = ((v.z - m) * is * wv.z + bv.z) * zv.z;
            v.w = ((v.w - m) * is * wv.w + bv.w) * zv.w;
            *(float4*)&gt[p * 104 + c4 * 4] = v;
        }
    }

    const int og = t & 31, pg = t >> 5;
    float acc[3][4];
#pragma unroll
    for (int i = 0; i < 3; ++i)
#pragma unroll
        for (int r = 0; r < 4; ++r) acc[i][r] = 0.f;

    for (int k0 = 0; k0 < Cn; k0 += 32) {
        __syncthreads();
        for (int e4 = t; e4 < 768; e4 += 512) {
            int o = e4 >> 3, c4 = e4 & 7;
            *(float4*)&wls[o * 36 + c4 * 4] = *(const float4*)&opw[o * Cn + k0 + c4 * 4];
        }
        __syncthreads();
#pragma unroll
        for (int c4 = 0; c4 < 8; ++c4) {
            float4 w0 = *(const float4*)&wls[(og * 3 + 0) * 36 + c4 * 4];
            float4 w1 = *(const float4*)&wls[(og * 3 + 1) * 36 + c4 * 4];
            float4 w2 = *(const float4*)&wls[(og * 3 + 2) * 36 + c4 * 4];
            float4 g0 = *(const float4*)&gt[(pg * 4 + 0) * 104 + k0 + c4 * 4];
            float4 g1 = *(const float4*)&gt[(pg * 4 + 1) * 104 + k0 + c4 * 4];
            float4 g2 = *(const float4*)&gt[(pg * 4 + 2) * 104 + k0 + c4 * 4];
            float4 g3 = *(const float4*)&gt[(pg * 4 + 3) * 104 + k0 + c4 * 4];
#define ACC1(i, wv, r, gv) \
            acc[i][r] = fmaf(wv.x, gv.x, acc[i][r]); \
            acc[i][r] = fmaf(wv.y, gv.y, acc[i][r]); \
            acc[i][r] = fmaf(wv.z, gv.z, acc[i][r]); \
            acc[i][r] = fmaf(wv.w, gv.w, acc[i][r]);
            ACC1(0, w0, 0, g0) ACC1(0, w0, 1, g1) ACC1(0, w0, 2, g2) ACC1(0, w0, 3, g3)
            ACC1(1, w1, 0, g0) ACC1(1, w1, 1, g1) ACC1(1, w1, 2, g2) ACC1(1, w1, 3, g3)
            ACC1(2, w2, 0, g0) ACC1(2, w2, 1, g1) ACC1(2, w2, 2, g2) ACC1(2, w2, 3, g3)
#undef ACC1
        }
    }

    __syncthreads();
#pragma unroll
    for (int i = 0; i < 3; ++i)
#pragma unroll
        for (int r = 0; r < 4; ++r)
            gt[(og * 3 + i) * 68 + pg * 4 + r] = acc[i][r];
    __syncthreads();

    {
        float* ob = out + (size_t)b * Cn * Ln + l0;
        for (int e4 = t; e4 < 1536; e4 += 512) {
            int o = e4 >> 4, p4 = e4 & 15;
            float4 v = *(const float4*)&gt[o * 68 + p4 * 4];
            float sc = scw[o];
            v.x *= sc; v.y *= sc; v.z *= sc; v.w *= sc;
            *(float4*)&ob[(size_t)o * Ln + p4 * 4] = v;
        }
    }
}

// ---------------------------------------------------------------------------
extern "C" void kernel_launch(void* const* d_in, const int* in_sizes, int n_in,
                              void* d_out, int out_size, void* d_ws, size_t ws_size,
                              hipStream_t stream)
{
    const float* x     = (const float*)d_in[0];
    const float* ipw   = (const float*)d_in[1];
    const float* cw    = (const float*)d_in[2];
    const float* cb    = (const float*)d_in[3];
    const float* xpw   = (const float*)d_in[4];
    const float* dtw   = (const float*)d_in[5];
    const float* dtb   = (const float*)d_in[6];
    const float* Alogs = (const float*)d_in[7];
    const float* Ds    = (const float*)d_in[8];
    const float* onw   = (const float*)d_in[9];
    const float* onb   = (const float*)d_in[10];
    const float* opw   = (const float*)d_in[11];
    const float* scw   = (const float*)d_in[12];
    float* out = (float*)d_out;

    // Workspace (float units), total 21.24M floats == prior proven footprint:
    //   xc   fp32  A        (A = Bn*Ln*Cn = 6.29M)
    //   zs   fp16  A/2
    //   y0h  fp16  A/2
    //   f    fp16  A        ([b][l][k][c], 2*Cn halfs/pos)
    //   Pc/Qc/hinit fp32 3*0.786M
    float* wsp = (float*)d_ws;
    const size_t A = (size_t)Bn * Ln * Cn;
    const size_t S = (size_t)Bn * Kn * NCH * Cn;
    float*  xc   = wsp;
    __half* zs   = (__half*)(wsp + A);
    __half* y0h  = (__half*)(wsp + A + A / 2);
    __half* f    = (__half*)(wsp + 2 * A);
    float*  Pc    = wsp + 3 * A;
    float*  Qc    = wsp + 3 * A + S;
    float*  hinit = wsp + 3 * A + 2 * S;

    k_inproj<<<Bn * 128, 256, 0, stream>>>(x, ipw, xc, zs);
    k_part1 <<<Bn * 512, 384, 0, stream>>>(xc, cw, cb, xpw, dtw, dtb, Alogs, Ds,
                                           Pc, Qc, y0h, f);
    k_scan2 <<<24, 1024, 0, stream>>>(Pc, Qc, hinit);
    k_merge <<<Bn * 256, 512, 0, stream>>>(y0h, f, hinit, zs, onw, onb,
                                           opw, scw, out);
}

// Round 8
// 246.812 us; speedup vs baseline: 1.1837x; 1.0796x over previous
//
#include <hip/hip_runtime.h>
#include <hip/hip_fp16.h>
#include <math.h>

#define Bn 4
#define Cn 96
#define Hn 128
#define Wn 128
#define Ln (Hn*Wn)      // 16384
#define Kn 2
#define Rn 6
#define SC 16           // scan chunk length
#define NCH (Ln/SC)     // 1024 chunks per (b,k)

typedef _Float16 f16;
typedef __attribute__((ext_vector_type(8))) _Float16 f16x8;
typedef __attribute__((ext_vector_type(4))) float f32x4;

__device__ __forceinline__ float siluf(float x) { return x / (1.f + __expf(-x)); }
// native-instruction softplus: log1pf is a slow libm polynomial; __logf(1+e)
// is v_log_f32 with abs err < 1e-7 over our range (tolerance 2.5e-2).
__device__ __forceinline__ float softplusf(float x) {
    return fmaxf(x, 0.f) + __logf(1.f + __expf(-fabsf(x)));
}

// ---------------------------------------------------------------------------
// Kernel A: in_proj GEMM, fp32 vector (R3-proven).  R7 post-mortem: f16 MFMA
// here fails tolerance -- in_proj error amplifies through scan recurrence and
// LayerNorm (absmax 0.037 > 0.025).  x (B,C,L) -> xc (B,L,C), zs (B,L,C).
// ---------------------------------------------------------------------------
__global__ __launch_bounds__(256, 3) void k_inproj(
    const float* __restrict__ x, const float* __restrict__ ipw,
    float* __restrict__ xc, float* __restrict__ zs)
{
    __shared__ float smem[4096 + 6272];
    float* xls = smem;
    float* wls = smem + 4096;
    float* stage = smem;

    const int t  = threadIdx.x;
    const int b  = blockIdx.x >> 7;
    const int l0 = (blockIdx.x & 127) << 7;
    const int tx = t & 15;
    const int ty = t >> 4;

    float acc[12][8];
#pragma unroll
    for (int i = 0; i < 12; ++i)
#pragma unroll
        for (int j = 0; j < 8; ++j) acc[i][j] = 0.f;

    const float* xbase = x + (size_t)b * Cn * Ln + l0;

    for (int k0 = 0; k0 < Cn; k0 += 32) {
        if (k0) __syncthreads();
        {
            int idx = t;
#pragma unroll
            for (int q = 0; q < 4; ++q, idx += 256) {
                int k = idx >> 5, p4 = idx & 31;
                *(float4*)&xls[k * 128 + p4 * 4] =
                    *(const float4*)&xbase[(size_t)(k0 + k) * Ln + p4 * 4];
            }
        }
        for (int idx = t; idx < 32 * 192; idx += 256) {
            int o = idx % 192, k = idx / 192;
            wls[k * 196 + o] = ipw[o * Cn + k0 + k];
        }
        __syncthreads();

#pragma unroll 2
        for (int kk = 0; kk < 32; ++kk) {
            float4 xv0 = *(const float4*)&xls[kk * 128 + tx * 4];
            float4 xv1 = *(const float4*)&xls[kk * 128 + 64 + tx * 4];
            const float* wrow = &wls[kk * 196 + ty * 12];
            float4 w0 = *(const float4*)&wrow[0];
            float4 w1 = *(const float4*)&wrow[4];
            float4 w2 = *(const float4*)&wrow[8];
            float wv[12] = {w0.x,w0.y,w0.z,w0.w,w1.x,w1.y,w1.z,w1.w,w2.x,w2.y,w2.z,w2.w};
            float xa[8]  = {xv0.x,xv0.y,xv0.z,xv0.w,xv1.x,xv1.y,xv1.z,xv1.w};
#pragma unroll
            for (int i = 0; i < 12; ++i)
#pragma unroll
                for (int j = 0; j < 8; ++j)
                    acc[i][j] = fmaf(wv[i], xa[j], acc[i][j]);
        }
    }

    const size_t tilebase = (size_t)b * Ln + l0;
#pragma unroll
    for (int half_ = 0; half_ < 2; ++half_) {
        __syncthreads();
        if (ty < 8) {
#pragma unroll
            for (int j = 0; j < 4; ++j)
#pragma unroll
                for (int i = 0; i < 12; ++i)
                    stage[(tx * 4 + j) * 100 + ty * 12 + i] = acc[i][half_ * 4 + j];
        }
        __syncthreads();
        {
            float4* dst = (float4*)(xc + (tilebase + half_ * 64) * Cn);
            for (int idx = t; idx < 1536; idx += 256) {
                int p = idx / 24, c4 = idx % 24;
                dst[idx] = *(const float4*)&stage[p * 100 + c4 * 4];
            }
        }
        __syncthreads();
        if (ty >= 8) {
#pragma unroll
            for (int j = 0; j < 4; ++j)
#pragma unroll
                for (int i = 0; i < 12; ++i)
                    stage[(tx * 4 + j) * 100 + (ty - 8) * 12 + i] = siluf(acc[i][half_ * 4 + j]);
        }
        __syncthreads();
        {
            float4* dst = (float4*)(zs + (tilebase + half_ * 64) * Cn);
            for (int idx = t; idx < 1536; idx += 256) {
                int p = idx / 24, c4 = idx % 24;
                dst[idx] = *(const float4*)&stage[p * 100 + c4 * 4];
            }
        }
    }
}

// ---------------------------------------------------------------------------
// Kernel B: depthwise 3x3 conv (SAME) + bias + SiLU, float4 over channels.
// ---------------------------------------------------------------------------
__global__ __launch_bounds__(256) void k_conv(
    const float* __restrict__ xc, const float* __restrict__ cw,
    const float* __restrict__ cb, float* __restrict__ u)
{
    __shared__ float cws[9 * 96];   // [tap][c]
    for (int i = threadIdx.x; i < 864; i += 256) {
        int cc = i % 96, tap = i / 96;
        cws[tap * 96 + cc] = cw[cc * 9 + tap];
    }
    __syncthreads();

    const int e   = blockIdx.x * 256 + threadIdx.x;
    const int c4  = e % 24;
    const int pos = e / 24;
    const int l   = pos % Ln;
    const int b   = pos / Ln;
    const int h   = l >> 7, w = l & 127;
    const int c   = c4 * 4;

    float4 acc = *(const float4*)&cb[c];
#pragma unroll
    for (int dh = -1; dh <= 1; ++dh) {
        int hh = h + dh;
        if (hh < 0 || hh >= Hn) continue;
#pragma unroll
        for (int dw = -1; dw <= 1; ++dw) {
            int ww = w + dw;
            if (ww < 0 || ww >= Wn) continue;
            float4 wv = *(const float4*)&cws[((dh + 1) * 3 + (dw + 1)) * 96 + c];
            float4 xv = *(const float4*)&xc[((size_t)b * Ln + (hh << 7) + ww) * Cn + c];
            acc.x = fmaf(wv.x, xv.x, acc.x);
            acc.y = fmaf(wv.y, xv.y, acc.y);
            acc.z = fmaf(wv.z, xv.z, acc.z);
            acc.w = fmaf(wv.w, xv.w, acc.w);
        }
    }
    float4 r;
    r.x = siluf(acc.x); r.y = siluf(acc.y); r.z = siluf(acc.z); r.w = siluf(acc.w);
    *(float4*)&u[((size_t)b * Ln + l) * Cn + c] = r;
}

// ---------------------------------------------------------------------------
// Kernel C (k_part1): R3-proven version, untouched (66 us local optimum).
// ---------------------------------------------------------------------------
__global__ __launch_bounds__(384, 4) void k_part1(
    const float* __restrict__ u, const float* __restrict__ xpw,
    const float* __restrict__ dtw, const float* __restrict__ dtb,
    const float* __restrict__ Alogs, const float* __restrict__ Ds,
    float* __restrict__ Pc, float* __restrict__ Qc,
    float* __restrict__ y0, __half* __restrict__ f)
{
    __shared__ float uls[32 * 100];  // [p][c] pad 100; reused as y-merge buffer
    __shared__ float xd[32 * 16];    // [p][dd] dd=k*8+d
    __shared__ float dsum[96];
    const int t  = threadIdx.x;
    const int j  = blockIdx.x & 511;
    const int b  = blockIdx.x >> 9;
    const int l0 = j << 5;

    {
        const float4* up4 = (const float4*)(u + ((size_t)b * Ln + l0) * Cn);
        for (int e4 = t; e4 < 768; e4 += 384) {
            int p = e4 / 24, c4 = e4 % 24;
            *(float4*)&uls[p * 100 + c4 * 4] = up4[e4];
        }
    }
    if (t < 96) dsum[t] = Ds[t] + Ds[Cn + t];
    __syncthreads();   // all u loads in LDS before any f-store below (alias!)

    for (int dp = t; dp < 512; dp += 384) {
        int dd = dp & 15, p = dp >> 4;
        const float4* wr = (const float4*)(xpw + dd * Cn);
        const float4* ur = (const float4*)&uls[p * 100];
        float acc = 0.f;
#pragma unroll
        for (int c4 = 0; c4 < 24; ++c4) {
            float4 w = wr[c4], v = ur[c4];
            acc = fmaf(w.x, v.x, acc); acc = fmaf(w.y, v.y, acc);
            acc = fmaf(w.z, v.z, acc); acc = fmaf(w.w, v.w, acc);
        }
        xd[p * 16 + dd] = acc;
    }
    __syncthreads();

    const int c  = t % 96;
    const int ci = (t / 96) & 1;
    const int k  = t / 192;
    const int bk = b * Kn + k;
    const float Av = -__expf(Alogs[k * Cn + c]);
    const float bias = dtb[k * Cn + c];
    const float dsc = dsum[c];
    float dtwr[Rn];
#pragma unroll
    for (int r = 0; r < Rn; ++r) dtwr[r] = dtw[(k * Cn + c) * Rn + r];

    const int chunk = (k == 0) ? (2 * j + ci) : (1022 - 2 * j + ci);
    const int xoff = k * 8;
    __half* fkc = f + ((size_t)(b * Ln + l0) * 2 + k) * Cn + c;

    float h = 0.f, cp = 1.f;
    float yreg[SC];
#pragma unroll
    for (int hf = 0; hf < 2; ++hf) {
        float dAv[8], dBu[8], Cl[8], uv[8];
#pragma unroll
        for (int i = 0; i < 8; ++i) {
            const int ii = hf * 8 + i;
            const int p = (k == 0) ? (ci * 16 + ii) : ((1 - ci) * 16 + (15 - ii));
            const float* xr = &xd[p * 16 + xoff];
            float de = bias;
#pragma unroll
            for (int r = 0; r < Rn; ++r) de = fmaf(dtwr[r], xr[r], de);
            de = softplusf(de);
            uv[i]  = uls[p * 100 + c];
            dAv[i] = __expf(de * Av);
            dBu[i] = de * uv[i] * xr[6];
            Cl[i]  = xr[7];
        }
#pragma unroll
        for (int i = 0; i < 8; ++i) {
            const int ii = hf * 8 + i;
            const int p = (k == 0) ? (ci * 16 + ii) : ((1 - ci) * 16 + (15 - ii));
            h  = fmaf(dAv[i], h, dBu[i]);
            cp *= dAv[i];
            yreg[ii] = (k == 0) ? fmaf(dsc, uv[i], h * Cl[i]) : (h * Cl[i]);
            fkc[(size_t)p * (2 * Cn)] = __float2half(cp * Cl[i]);
        }
    }
    {
        const size_t cidx = ((size_t)bk * NCH + chunk) * Cn + c;
        Pc[cidx] = cp;
        Qc[cidx] = h;
    }

    __syncthreads();   // all uls reads done
    if (k == 0) {
#pragma unroll
        for (int i = 0; i < SC; ++i) {
            int p = ci * 16 + i;
            uls[p * 100 + c] = yreg[i];
        }
    }
    __syncthreads();
    if (k == 1) {
#pragma unroll
        for (int i = 0; i < SC; ++i) {
            int p = (1 - ci) * 16 + (15 - i);
            uls[p * 100 + c] += yreg[i];
        }
    }
    __syncthreads();
    {
        float4* y4 = (float4*)(y0 + ((size_t)b * Ln + l0) * Cn);
        for (int e4 = t; e4 < 768; e4 += 384) {
            int p = e4 / 24, c4 = e4 % 24;
            y4[e4] = *(const float4*)&uls[p * 100 + c4 * 4];
        }
    }
}

// ---------------------------------------------------------------------------
// Kernel D: hierarchical carry scan (unchanged). 768 series x 1024 chunks.
// ---------------------------------------------------------------------------
__global__ __launch_bounds__(1024) void k_scan2(
    const float* __restrict__ Pc, const float* __restrict__ Qc,
    float* __restrict__ hinit)
{
    __shared__ float Pg[32][33], Qg[32][33], gini[32][33];
    const int bk    = blockIdx.x / 3;
    const int cbase = (blockIdx.x % 3) * 32;
    const int t = threadIdx.x;
    const int c = t & 31, g = t >> 5;

    const size_t base = ((size_t)bk * NCH + g * 32) * Cn + cbase + c;
    float P = 1.f, Q = 0.f;
    for (int j = 0; j < 32; ++j) {
        size_t idx = base + (size_t)j * Cn;
        float p_ = Pc[idx], q_ = Qc[idx];
        Q = fmaf(p_, Q, q_);
        P *= p_;
    }
    Pg[g][c] = P; Qg[g][c] = Q;
    __syncthreads();
    if (t < 32) {
        float h = 0.f;
        for (int gg = 0; gg < 32; ++gg) {
            gini[gg][t] = h;
            h = fmaf(Pg[gg][t], h, Qg[gg][t]);
        }
    }
    __syncthreads();
    float h = gini[g][c];
    for (int j = 0; j < 32; ++j) {
        size_t idx = base + (size_t)j * Cn;
        hinit[idx] = h;
        h = fmaf(Pc[idx], h, Qc[idx]);
    }
}

// ---------------------------------------------------------------------------
// Kernel E (k_merge): merge + LN + gate + MFMA out_proj GEMM (R7, validated
// numerically: out_proj f16 error is terminal, ~1e-3 worst case).
// 8 waves = 4 m-tiles x 2 n-halves; fragment-linear LDS (one b128/frag);
// fp32 accum; 9 mfma/wave replaces the 3-pass vector GEMM (6 barriers).
// ---------------------------------------------------------------------------
__global__ __launch_bounds__(512) void k_merge(
    const float* __restrict__ y0, const __half* __restrict__ f,
    const float* __restrict__ hinit, const float* __restrict__ zs,
    const float* __restrict__ onw, const float* __restrict__ onb,
    const float* __restrict__ opw, const float* __restrict__ scw,
    float* __restrict__ out)
{
    __shared__ float gt[64 * 104];   // y tile; reused as outT[o][68] after gate
    __shared__ f16  gh[4 * 3 * 64 * 8];    // g frags  [mt][kb][64][8] 12.3KB
    __shared__ f16  oph[6 * 3 * 64 * 8];   // w frags  [nt][kb][64][8] 18.4KB
    __shared__ float h0s[4 * 96], h1s[4 * 96];
    __shared__ float mu[64], isd[64];
    const int t  = threadIdx.x;
    const int j  = blockIdx.x & 255;
    const int b  = blockIdx.x >> 8;
    const int l0 = j << 6;

    // stage opw frags (L2-served) + hinit
    {
        const float4* w4 = (const float4*)opw;
        for (int i = t; i < 2304; i += 512) {
            int o = i / 24, c4 = i % 24;
            float4 v = w4[i];
            int nt = o >> 4, fr = o & 15, kb = c4 >> 3, fg = (c4 >> 1) & 3;
            f16* d = &oph[(((nt * 3 + kb) * 64) + fg * 16 + fr) * 8 + (c4 & 1) * 4];
            d[0] = (f16)v.x; d[1] = (f16)v.y; d[2] = (f16)v.z; d[3] = (f16)v.w;
        }
    }
    for (int idx = t; idx < 768; idx += 512) {
        if (idx < 384) {
            int q = idx / 96, c = idx % 96;
            h0s[q * 96 + c] = hinit[((size_t)(b * 2 + 0) * NCH + 4 * j + q) * Cn + c];
        } else {
            int i2 = idx - 384;
            int q = i2 / 96, c = i2 % 96;
            h1s[q * 96 + c] = hinit[((size_t)(b * 2 + 1) * NCH + (1023 - 4 * j - q)) * Cn + c];
        }
    }
    __syncthreads();

    // elementwise merge: y = y0 + h0*f0 + h1*f1  -> gt[p][c]
    {
        const float4* y4 = (const float4*)(y0 + ((size_t)b * Ln + l0) * Cn);
        const __half* fb = f + (size_t)(b * Ln + l0) * 2 * Cn;
        for (int e4 = t; e4 < 1536; e4 += 512) {
            int p = e4 / 24, c4 = e4 % 24;
            float4 yv = y4[e4];
            const __half* fp0 = fb + (size_t)p * (2 * Cn) + c4 * 4;
            const __half2* f0h = (const __half2*)fp0;
            const __half2* f1h = (const __half2*)(fp0 + Cn);
            float2 fa0 = __half22float2(f0h[0]);
            float2 fa1 = __half22float2(f0h[1]);
            float2 fb0 = __half22float2(f1h[0]);
            float2 fb1 = __half22float2(f1h[1]);
            const float4 h0v = *(const float4*)&h0s[(p >> 4) * 96 + c4 * 4];
            const float4 h1v = *(const float4*)&h1s[(p >> 4) * 96 + c4 * 4];
            yv.x = fmaf(h0v.x, fa0.x, fmaf(h1v.x, fb0.x, yv.x));
            yv.y = fmaf(h0v.y, fa0.y, fmaf(h1v.y, fb0.y, yv.y));
            yv.z = fmaf(h0v.z, fa1.x, fmaf(h1v.z, fb1.x, yv.z));
            yv.w = fmaf(h0v.w, fa1.y, fmaf(h1v.w, fb1.y, yv.w));
            *(float4*)&gt[p * 104 + c4 * 4] = yv;
        }
    }
    __syncthreads();

    if (t < 256) {
        const int p = t >> 2, q = t & 3;
        const float4* row = (const float4*)&gt[p * 104 + q * 24];
        float s = 0.f, ss = 0.f;
#pragma unroll
        for (int i = 0; i < 6; ++i) {
            float4 v = row[i];
            s  += v.x + v.y + v.z + v.w;
            ss += v.x*v.x + v.y*v.y + v.z*v.z + v.w*v.w;
        }
        s  += __shfl_xor(s, 1);  s  += __shfl_xor(s, 2);
        ss += __shfl_xor(ss, 1); ss += __shfl_xor(ss, 2);
        if (q == 0) {
            float m = s * (1.f / Cn);
            mu[p] = m;
            isd[p] = rsqrtf(ss * (1.f / Cn) - m * m + 1e-5f);
        }
    }
    __syncthreads();

    // gate: read gt, write f16 frags gh (gt itself becomes dead -> outT)
    {
        const float4* zp4 = (const float4*)(zs + ((size_t)b * Ln + l0) * Cn);
        const float4* w4  = (const float4*)onw;
        const float4* b4  = (const float4*)onb;
        for (int e4 = t; e4 < 1536; e4 += 512) {
            int p = e4 / 24, c4 = e4 % 24;
            float4 v = *(const float4*)&gt[p * 104 + c4 * 4];
            float4 wv = w4[c4], bv = b4[c4], zv = zp4[e4];
            float m = mu[p], is = isd[p];
            v.x = ((v.x - m) * is * wv.x + bv.x) * zv.x;
            v.y = ((v.y - m) * is * wv.y + bv.y) * zv.y;
            v.z = ((v.z - m) * is * wv.z + bv.z) * zv.z;
            v.w = ((v.w - m) * is * wv.w + bv.w) * zv.w;
            int mt = p >> 4, fr = p & 15, kb = c4 >> 3, fg = (c4 >> 1) & 3;
            f16* d = &gh[(((mt * 3 + kb) * 64) + fg * 16 + fr) * 8 + (c4 & 1) * 4];
            d[0] = (f16)v.x; d[1] = (f16)v.y; d[2] = (f16)v.z; d[3] = (f16)v.w;
        }
    }
    __syncthreads();

    // MFMA: wave wv -> m-tile mt = wv>>1, n-half nh = wv&1 (3 n-tiles each)
    const int wv = t >> 6, ln = t & 63;
    const int fr = ln & 15, fg = ln >> 4;
    const int mt = wv >> 1, nh = wv & 1;
    f32x4 acc[3];
#pragma unroll
    for (int i = 0; i < 3; ++i) acc[i] = (f32x4){0.f, 0.f, 0.f, 0.f};
#pragma unroll
    for (int kb = 0; kb < 3; ++kb) {
        f16x8 af = *(const f16x8*)&gh[((mt * 3 + kb) * 64 + ln) * 8];
#pragma unroll
        for (int ntl = 0; ntl < 3; ++ntl) {
            int nt = nh * 3 + ntl;
            f16x8 bf = *(const f16x8*)&oph[((nt * 3 + kb) * 64 + ln) * 8];
            acc[ntl] = __builtin_amdgcn_mfma_f32_16x16x32_f16(af, bf, acc[ntl], 0, 0, 0);
        }
    }
    // D -> outT (aliases gt): o = nt*16+fr, p = mt*16 + fg*4 + j
#pragma unroll
    for (int ntl = 0; ntl < 3; ++ntl)
#pragma unroll
        for (int jj = 0; jj < 4; ++jj)
            gt[((nh * 3 + ntl) * 16 + fr) * 68 + mt * 16 + fg * 4 + jj] = acc[ntl][jj];
    __syncthreads();

    {
        float* ob = out + (size_t)b * Cn * Ln + l0;
        for (int e4 = t; e4 < 1536; e4 += 512) {
            int o = e4 >> 4, p4 = e4 & 15;
            float4 v = *(const float4*)&gt[o * 68 + p4 * 4];
            float sc = scw[o];
            v.x *= sc; v.y *= sc; v.z *= sc; v.w *= sc;
            *(float4*)&ob[(size_t)o * Ln + p4 * 4] = v;
        }
    }
}

// ---------------------------------------------------------------------------
extern "C" void kernel_launch(void* const* d_in, const int* in_sizes, int n_in,
                              void* d_out, int out_size, void* d_ws, size_t ws_size,
                              hipStream_t stream)
{
    const float* x     = (const float*)d_in[0];
    const float* ipw   = (const float*)d_in[1];
    const float* cw    = (const float*)d_in[2];
    const float* cb    = (const float*)d_in[3];
    const float* xpw   = (const float*)d_in[4];
    const float* dtw   = (const float*)d_in[5];
    const float* dtb   = (const float*)d_in[6];
    const float* Alogs = (const float*)d_in[7];
    const float* Ds    = (const float*)d_in[8];
    const float* onw   = (const float*)d_in[9];
    const float* onb   = (const float*)d_in[10];
    const float* opw   = (const float*)d_in[11];
    const float* scw   = (const float*)d_in[12];
    float* out = (float*)d_out;

    float* wsp = (float*)d_ws;
    size_t off = 0;
    // xc dead after k_conv -> y0 aliases it
    float* xc   = wsp + off;
    float* y0   = wsp + off; off += (size_t)Bn * Ln * Cn;         // 6.29M
    float* zs   = wsp + off; off += (size_t)Bn * Ln * Cn;         // 6.29M
    float* u    = wsp + off; off += (size_t)Bn * Ln * Cn;         // 6.29M
    // f (fp16, [b][l][k][c]) overlays u byte-exactly per position; each part1
    // block consumes its own u range into LDS (barrier) before overwriting it.
    __half* f   = (__half*)u;
    float* Pc    = wsp + off; off += (size_t)Bn * Kn * NCH * Cn;  // 0.79M
    float* Qc    = wsp + off; off += (size_t)Bn * Kn * NCH * Cn;
    float* hinit = wsp + off; off += (size_t)Bn * Kn * NCH * Cn;

    k_inproj<<<Bn * 128, 256, 0, stream>>>(x, ipw, xc, zs);
    k_conv  <<<(Bn * Ln * 24) / 256, 256, 0, stream>>>(xc, cw, cb, u);
    k_part1 <<<Bn * 512, 384, 0, stream>>>(u, xpw, dtw, dtb, Alogs, Ds,
                                           Pc, Qc, y0, f);
    k_scan2 <<<24, 1024, 0, stream>>>(Pc, Qc, hinit);
    k_merge <<<Bn * 256, 512, 0, stream>>>(y0, f, hinit, zs, onw, onb,
                                           opw, scw, out);
}

// Round 13
// 238.316 us; speedup vs baseline: 1.2259x; 1.0357x over previous
//
#include <hip/hip_runtime.h>
#include <hip/hip_fp16.h>
#include <math.h>

#define Bn 4
#define Cn 96
#define Hn 128
#define Wn 128
#define Ln (Hn*Wn)      // 16384
#define Kn 2
#define Rn 6
#define SC 16           // scan chunk length
#define NCH (Ln/SC)     // 1024 chunks per (b,k)

__device__ __forceinline__ float siluf(float x) { return x / (1.f + __expf(-x)); }
// native-instruction softplus: log1pf is a slow libm polynomial; __logf(1+e)
// is v_log_f32 with abs err < 1e-7 over our range (tolerance 2.5e-2).
__device__ __forceinline__ float softplusf(float x) {
    return fmaxf(x, 0.f) + __logf(1.f + __expf(-fabsf(x)));
}

// ---------------------------------------------------------------------------
// NUMERICS / DETERMINISM LEDGER (empirical):
//   fp32 pipeline + f-fp16 (R1/R3)       = 0.001953125, BIT-STABLE across
//                                          rounds and graph replays. PASSED.
//   + f16-MFMA out_proj (R8/R12 family)  = 0.0117-0.0273, RUN-TO-RUN
//     NONDETERMINISTIC (R12: 0.0156 first -> 0.0273 post-timing; R9 drifted
//     too). Mechanism unfound after 3 audits; straddles the 0.0252
//     threshold -> ABANDONED.  zs/y0 fp16: FAILED (0.031-0.037, R7/R10/R11).
// This file: R1/R3 numerics (deterministic 0.00195) with every proven-safe
// speed lever: float4 conv, fused fp32 merge (no g round-trip), R3 part1
// with the value-identical GEMV remap (each half-wave broadcast-reads one
// xpw row -> 2 cache lines/instr instead of 16).
// ---------------------------------------------------------------------------

// ---------------------------------------------------------------------------
// Kernel A: in_proj GEMM, fp32 vector (R3-proven).
// x (B,C,L) -> xc (B,L,C) fp32, zs = silu(z) (B,L,C) fp32.
// ---------------------------------------------------------------------------
__global__ __launch_bounds__(256, 3) void k_inproj(
    const float* __restrict__ x, const float* __restrict__ ipw,
    float* __restrict__ xc, float* __restrict__ zs)
{
    __shared__ float smem[4096 + 6272];
    float* xls = smem;
    float* wls = smem + 4096;
    float* stage = smem;

    const int t  = threadIdx.x;
    const int b  = blockIdx.x >> 7;
    const int l0 = (blockIdx.x & 127) << 7;
    const int tx = t & 15;
    const int ty = t >> 4;

    float acc[12][8];
#pragma unroll
    for (int i = 0; i < 12; ++i)
#pragma unroll
        for (int j = 0; j < 8; ++j) acc[i][j] = 0.f;

    const float* xbase = x + (size_t)b * Cn * Ln + l0;

    for (int k0 = 0; k0 < Cn; k0 += 32) {
        if (k0) __syncthreads();
        {
            int idx = t;
#pragma unroll
            for (int q = 0; q < 4; ++q, idx += 256) {
                int k = idx >> 5, p4 = idx & 31;
                *(float4*)&xls[k * 128 + p4 * 4] =
                    *(const float4*)&xbase[(size_t)(k0 + k) * Ln + p4 * 4];
            }
        }
        for (int idx = t; idx < 32 * 192; idx += 256) {
            int o = idx % 192, k = idx / 192;
            wls[k * 196 + o] = ipw[o * Cn + k0 + k];
        }
        __syncthreads();

#pragma unroll 2
        for (int kk = 0; kk < 32; ++kk) {
            float4 xv0 = *(const float4*)&xls[kk * 128 + tx * 4];
            float4 xv1 = *(const float4*)&xls[kk * 128 + 64 + tx * 4];
            const float* wrow = &wls[kk * 196 + ty * 12];
            float4 w0 = *(const float4*)&wrow[0];
            float4 w1 = *(const float4*)&wrow[4];
            float4 w2 = *(const float4*)&wrow[8];
            float wv[12] = {w0.x,w0.y,w0.z,w0.w,w1.x,w1.y,w1.z,w1.w,w2.x,w2.y,w2.z,w2.w};
            float xa[8]  = {xv0.x,xv0.y,xv0.z,xv0.w,xv1.x,xv1.y,xv1.z,xv1.w};
#pragma unroll
            for (int i = 0; i < 12; ++i)
#pragma unroll
                for (int j = 0; j < 8; ++j)
                    acc[i][j] = fmaf(wv[i], xa[j], acc[i][j]);
        }
    }

    const size_t tilebase = (size_t)b * Ln + l0;
#pragma unroll
    for (int half_ = 0; half_ < 2; ++half_) {
        __syncthreads();
        if (ty < 8) {
#pragma unroll
            for (int j = 0; j < 4; ++j)
#pragma unroll
                for (int i = 0; i < 12; ++i)
                    stage[(tx * 4 + j) * 100 + ty * 12 + i] = acc[i][half_ * 4 + j];
        }
        __syncthreads();
        {
            float4* dst = (float4*)(xc + (tilebase + half_ * 64) * Cn);
            for (int idx = t; idx < 1536; idx += 256) {
                int p = idx / 24, c4 = idx % 24;
                dst[idx] = *(const float4*)&stage[p * 100 + c4 * 4];
            }
        }
        __syncthreads();
        if (ty >= 8) {
#pragma unroll
            for (int j = 0; j < 4; ++j)
#pragma unroll
                for (int i = 0; i < 12; ++i)
                    stage[(tx * 4 + j) * 100 + (ty - 8) * 12 + i] = siluf(acc[i][half_ * 4 + j]);
        }
        __syncthreads();
        {
            float4* dst = (float4*)(zs + (tilebase + half_ * 64) * Cn);
            for (int idx = t; idx < 1536; idx += 256) {
                int p = idx / 24, c4 = idx % 24;
                dst[idx] = *(const float4*)&stage[p * 100 + c4 * 4];
            }
        }
    }
}

// ---------------------------------------------------------------------------
// Kernel B: depthwise 3x3 conv (SAME) + bias + SiLU, float4 over channels.
// ---------------------------------------------------------------------------
__global__ __launch_bounds__(256) void k_conv(
    const float* __restrict__ xc, const float* __restrict__ cw,
    const float* __restrict__ cb, float* __restrict__ u)
{
    __shared__ float cws[9 * 96];   // [tap][c]
    for (int i = threadIdx.x; i < 864; i += 256) {
        int cc = i % 96, tap = i / 96;
        cws[tap * 96 + cc] = cw[cc * 9 + tap];
    }
    __syncthreads();

    const int e   = blockIdx.x * 256 + threadIdx.x;
    const int c4  = e % 24;
    const int pos = e / 24;
    const int l   = pos % Ln;
    const int b   = pos / Ln;
    const int h   = l >> 7, w = l & 127;
    const int c   = c4 * 4;

    float4 acc = *(const float4*)&cb[c];
#pragma unroll
    for (int dh = -1; dh <= 1; ++dh) {
        int hh = h + dh;
        if (hh < 0 || hh >= Hn) continue;
#pragma unroll
        for (int dw = -1; dw <= 1; ++dw) {
            int ww = w + dw;
            if (ww < 0 || ww >= Wn) continue;
            float4 wv = *(const float4*)&cws[((dh + 1) * 3 + (dw + 1)) * 96 + c];
            float4 xv = *(const float4*)&xc[((size_t)b * Ln + (hh << 7) + ww) * Cn + c];
            acc.x = fmaf(wv.x, xv.x, acc.x);
            acc.y = fmaf(wv.y, xv.y, acc.y);
            acc.z = fmaf(wv.z, xv.z, acc.z);
            acc.w = fmaf(wv.w, xv.w, acc.w);
        }
    }
    float4 r;
    r.x = siluf(acc.x); r.y = siluf(acc.y); r.z = siluf(acc.z); r.w = siluf(acc.w);
    *(float4*)&u[((size_t)b * Ln + l) * Cn + c] = r;
}

// ---------------------------------------------------------------------------
// Kernel C (k_part1): R3-proven structure; GEMV (p,dd) remap so each
// half-wave broadcast-reads ONE xpw row (2 cache lines/instr vs 16).
// Value-identical per-dot fmaf chains; R1<->R3's larger thread remaps left
// absmax bit-stable, so this is numerics-safe in the fp32-merge regime.
// ---------------------------------------------------------------------------
__global__ __launch_bounds__(384, 4) void k_part1(
    const float* __restrict__ u, const float* __restrict__ xpw,
    const float* __restrict__ dtw, const float* __restrict__ dtb,
    const float* __restrict__ Alogs, const float* __restrict__ Ds,
    float* __restrict__ Pc, float* __restrict__ Qc,
    float* __restrict__ y0, __half* __restrict__ f)
{
    __shared__ float uls[32 * 100];  // [p][c] pad 100; reused as y-merge buffer
    __shared__ float xd[32 * 16];    // [p][dd] dd=k*8+d
    __shared__ float dsum[96];
    const int t  = threadIdx.x;
    const int j  = blockIdx.x & 511;
    const int b  = blockIdx.x >> 9;
    const int l0 = j << 5;

    {
        const float4* up4 = (const float4*)(u + ((size_t)b * Ln + l0) * Cn);
        for (int e4 = t; e4 < 768; e4 += 384) {
            int p = e4 / 24, c4 = e4 % 24;
            *(float4*)&uls[p * 100 + c4 * 4] = up4[e4];
        }
    }
    if (t < 96) dsum[t] = Ds[t] + Ds[Cn + t];
    __syncthreads();   // all u loads in LDS before any f-store below (alias!)

    for (int dp = t; dp < 512; dp += 384) {
        int p = dp & 31, dd = dp >> 5;     // broadcast-friendly remap
        const float4* wr = (const float4*)(xpw + dd * Cn);
        const float4* ur = (const float4*)&uls[p * 100];
        float acc = 0.f;
#pragma unroll
        for (int c4 = 0; c4 < 24; ++c4) {
            float4 w = wr[c4], v = ur[c4];
            acc = fmaf(w.x, v.x, acc); acc = fmaf(w.y, v.y, acc);
            acc = fmaf(w.z, v.z, acc); acc = fmaf(w.w, v.w, acc);
        }
        xd[p * 16 + dd] = acc;
    }
    __syncthreads();

    const int c  = t % 96;
    const int ci = (t / 96) & 1;
    const int k  = t / 192;
    const int bk = b * Kn + k;
    const float Av = -__expf(Alogs[k * Cn + c]);
    const float bias = dtb[k * Cn + c];
    const float dsc = dsum[c];
    float dtwr[Rn];
#pragma unroll
    for (int r = 0; r < Rn; ++r) dtwr[r] = dtw[(k * Cn + c) * Rn + r];

    const int chunk = (k == 0) ? (2 * j + ci) : (1022 - 2 * j + ci);
    const int xoff = k * 8;
    __half* fkc = f + ((size_t)(b * Ln + l0) * 2 + k) * Cn + c;

    float h = 0.f, cp = 1.f;
    float yreg[SC];
#pragma unroll
    for (int hf = 0; hf < 2; ++hf) {
        float dAv[8], dBu[8], Cl[8], uv[8];
#pragma unroll
        for (int i = 0; i < 8; ++i) {
            const int ii = hf * 8 + i;
            const int p = (k == 0) ? (ci * 16 + ii) : ((1 - ci) * 16 + (15 - ii));
            const float* xr = &xd[p * 16 + xoff];
            float de = bias;
#pragma unroll
            for (int r = 0; r < Rn; ++r) de = fmaf(dtwr[r], xr[r], de);
            de = softplusf(de);
            uv[i]  = uls[p * 100 + c];
            dAv[i] = __expf(de * Av);
            dBu[i] = de * uv[i] * xr[6];
            Cl[i]  = xr[7];
        }
#pragma unroll
        for (int i = 0; i < 8; ++i) {
            const int ii = hf * 8 + i;
            const int p = (k == 0) ? (ci * 16 + ii) : ((1 - ci) * 16 + (15 - ii));
            h  = fmaf(dAv[i], h, dBu[i]);
            cp *= dAv[i];
            yreg[ii] = (k == 0) ? fmaf(dsc, uv[i], h * Cl[i]) : (h * Cl[i]);
            fkc[(size_t)p * (2 * Cn)] = __float2half(cp * Cl[i]);
        }
    }
    {
        const size_t cidx = ((size_t)bk * NCH + chunk) * Cn + c;
        Pc[cidx] = cp;
        Qc[cidx] = h;
    }

    __syncthreads();   // all uls reads done
    if (k == 0) {
#pragma unroll
        for (int i = 0; i < SC; ++i) {
            int p = ci * 16 + i;
            uls[p * 100 + c] = yreg[i];
        }
    }
    __syncthreads();
    if (k == 1) {
#pragma unroll
        for (int i = 0; i < SC; ++i) {
            int p = (1 - ci) * 16 + (15 - i);
            uls[p * 100 + c] += yreg[i];
        }
    }
    __syncthreads();
    {
        float4* y4 = (float4*)(y0 + ((size_t)b * Ln + l0) * Cn);
        for (int e4 = t; e4 < 768; e4 += 384) {
            int p = e4 / 24, c4 = e4 % 24;
            y4[e4] = *(const float4*)&uls[p * 100 + c4 * 4];
        }
    }
}

// ---------------------------------------------------------------------------
// Kernel D: hierarchical carry scan (unchanged). 768 series x 1024 chunks.
// ---------------------------------------------------------------------------
__global__ __launch_bounds__(1024) void k_scan2(
    const float* __restrict__ Pc, const float* __restrict__ Qc,
    float* __restrict__ hinit)
{
    __shared__ float Pg[32][33], Qg[32][33], gini[32][33];
    const int bk    = blockIdx.x / 3;
    const int cbase = (blockIdx.x % 3) * 32;
    const int t = threadIdx.x;
    const int c = t & 31, g = t >> 5;

    const size_t base = ((size_t)bk * NCH + g * 32) * Cn + cbase + c;
    float P = 1.f, Q = 0.f;
    for (int j = 0; j < 32; ++j) {
        size_t idx = base + (size_t)j * Cn;
        float p_ = Pc[idx], q_ = Qc[idx];
        Q = fmaf(p_, Q, q_);
        P *= p_;
    }
    Pg[g][c] = P; Qg[g][c] = Q;
    __syncthreads();
    if (t < 32) {
        float h = 0.f;
        for (int gg = 0; gg < 32; ++gg) {
            gini[gg][t] = h;
            h = fmaf(Pg[gg][t], h, Qg[gg][t]);
        }
    }
    __syncthreads();
    float h = gini[g][c];
    for (int j = 0; j < 32; ++j) {
        size_t idx = base + (size_t)j * Cn;
        hinit[idx] = h;
        h = fmaf(Pc[idx], h, Qc[idx]);
    }
}

// ---------------------------------------------------------------------------
// Kernel E (k_merge): streaming merge + LN + gate + fused fp32 out_proj GEMM
// (R1-proven, deterministic 0.00195).  No g round-trip to HBM.
//   y = y0 + hinit0*f0 + hinit1*f1 ; LN ; *silu(z) ; out = opw @ g * scw
// ---------------------------------------------------------------------------
__global__ __launch_bounds__(512) void k_merge(
    const float* __restrict__ y0, const __half* __restrict__ f,
    const float* __restrict__ hinit, const float* __restrict__ zs,
    const float* __restrict__ onw, const float* __restrict__ onb,
    const float* __restrict__ opw, const float* __restrict__ scw,
    float* __restrict__ out)
{
    __shared__ float gt[64 * 104];   // y -> gated g -> reused as outT[o][68]
    __shared__ float wls[96 * 36];   // opw chunk [o][32] pad 36
    __shared__ float h0s[4 * 96], h1s[4 * 96];
    __shared__ float mu[64], isd[64];
    const int t  = threadIdx.x;
    const int j  = blockIdx.x & 255;
    const int b  = blockIdx.x >> 8;
    const int l0 = j << 6;

    for (int idx = t; idx < 768; idx += 512) {
        if (idx < 384) {
            int q = idx / 96, c = idx % 96;
            h0s[q * 96 + c] = hinit[((size_t)(b * 2 + 0) * NCH + 4 * j + q) * Cn + c];
        } else {
            int i2 = idx - 384;
            int q = i2 / 96, c = i2 % 96;
            h1s[q * 96 + c] = hinit[((size_t)(b * 2 + 1) * NCH + (1023 - 4 * j - q)) * Cn + c];
        }
    }
    __syncthreads();

    // elementwise merge: y = y0 + h0*f0 + h1*f1  -> gt[p][c]
    {
        const float4* y4 = (const float4*)(y0 + ((size_t)b * Ln + l0) * Cn);
        const __half* fb = f + (size_t)(b * Ln + l0) * 2 * Cn;
        for (int e4 = t; e4 < 1536; e4 += 512) {
            int p = e4 / 24, c4 = e4 % 24;
            float4 yv = y4[e4];
            const __half* fp0 = fb + (size_t)p * (2 * Cn) + c4 * 4;
            const __half2* f0h = (const __half2*)fp0;
            const __half2* f1h = (const __half2*)(fp0 + Cn);
            float2 fa0 = __half22float2(f0h[0]);
            float2 fa1 = __half22float2(f0h[1]);
            float2 fb0 = __half22float2(f1h[0]);
            float2 fb1 = __half22float2(f1h[1]);
            const float4 h0v = *(const float4*)&h0s[(p >> 4) * 96 + c4 * 4];
            const float4 h1v = *(const float4*)&h1s[(p >> 4) * 96 + c4 * 4];
            yv.x = fmaf(h0v.x, fa0.x, fmaf(h1v.x, fb0.x, yv.x));
            yv.y = fmaf(h0v.y, fa0.y, fmaf(h1v.y, fb0.y, yv.y));
            yv.z = fmaf(h0v.z, fa1.x, fmaf(h1v.z, fb1.x, yv.z));
            yv.w = fmaf(h0v.w, fa1.y, fmaf(h1v.w, fb1.y, yv.w));
            *(float4*)&gt[p * 104 + c4 * 4] = yv;
        }
    }
    __syncthreads();

    if (t < 256) {
        const int p = t >> 2, q = t & 3;
        const float4* row = (const float4*)&gt[p * 104 + q * 24];
        float s = 0.f, ss = 0.f;
#pragma unroll
        for (int i = 0; i < 6; ++i) {
            float4 v = row[i];
            s  += v.x + v.y + v.z + v.w;
            ss += v.x*v.x + v.y*v.y + v.z*v.z + v.w*v.w;
        }
        s  += __shfl_xor(s, 1);  s  += __shfl_xor(s, 2);
        ss += __shfl_xor(ss, 1); ss += __shfl_xor(ss, 2);
        if (q == 0) {
            float m = s * (1.f / Cn);
            mu[p] = m;
            isd[p] = rsqrtf(ss * (1.f / Cn) - m * m + 1e-5f);
        }
    }
    __syncthreads();

    // gate in place: gt[p][c] = ((y-mu)*isd*w + b) * silu-z
    {
        const float4* zp4 = (const float4*)(zs + ((size_t)b * Ln + l0) * Cn);
        const float4* w4  = (const float4*)onw;
        const float4* b4  = (const float4*)onb;
        for (int e4 = t; e4 < 1536; e4 += 512) {
            int p = e4 / 24, c4 = e4 % 24;
            float4 v = *(const float4*)&gt[p * 104 + c4 * 4];
            float4 wv = w4[c4], bv = b4[c4], zv = zp4[e4];
            float m = mu[p], is = isd[p];
            v.x = ((v.x - m) * is * wv.x + bv.x) * zv.x;
            v.y = ((v.y - m) * is * wv.y + bv.y) * zv.y;
            v.z = ((v.z - m) * is * wv.z + bv.z) * zv.z;
            v.w = ((v.w - m) * is * wv.w + bv.w) * zv.w;
            *(float4*)&gt[p * 104 + c4 * 4] = v;
        }
    }

    // fused out_proj GEMM (fp32 vector): out(o,p) = sum_c gt[p][c]*opw[o][c]
    const int og = t & 31, pg = t >> 5;
    float acc[3][4];
#pragma unroll
    for (int i = 0; i < 3; ++i)
#pragma unroll
        for (int r = 0; r < 4; ++r) acc[i][r] = 0.f;

    for (int k0 = 0; k0 < Cn; k0 += 32) {
        __syncthreads();
        for (int e4 = t; e4 < 768; e4 += 512) {
            int o = e4 >> 3, c4 = e4 & 7;
            *(float4*)&wls[o * 36 + c4 * 4] = *(const float4*)&opw[o * Cn + k0 + c4 * 4];
        }
        __syncthreads();
#pragma unroll
        for (int c4 = 0; c4 < 8; ++c4) {
            float4 w0 = *(const float4*)&wls[(og * 3 + 0) * 36 + c4 * 4];
            float4 w1 = *(const float4*)&wls[(og * 3 + 1) * 36 + c4 * 4];
            float4 w2 = *(const float4*)&wls[(og * 3 + 2) * 36 + c4 * 4];
            float4 g0 = *(const float4*)&gt[(pg * 4 + 0) * 104 + k0 + c4 * 4];
            float4 g1 = *(const float4*)&gt[(pg * 4 + 1) * 104 + k0 + c4 * 4];
            float4 g2 = *(const float4*)&gt[(pg * 4 + 2) * 104 + k0 + c4 * 4];
            float4 g3 = *(const float4*)&gt[(pg * 4 + 3) * 104 + k0 + c4 * 4];
#define ACC1(i, wv, r, gv) \
            acc[i][r] = fmaf(wv.x, gv.x, acc[i][r]); \
            acc[i][r] = fmaf(wv.y, gv.y, acc[i][r]); \
            acc[i][r] = fmaf(wv.z, gv.z, acc[i][r]); \
            acc[i][r] = fmaf(wv.w, gv.w, acc[i][r]);
            ACC1(0, w0, 0, g0) ACC1(0, w0, 1, g1) ACC1(0, w0, 2, g2) ACC1(0, w0, 3, g3)
            ACC1(1, w1, 0, g0) ACC1(1, w1, 1, g1) ACC1(1, w1, 2, g2) ACC1(1, w1, 3, g3)
            ACC1(2, w2, 0, g0) ACC1(2, w2, 1, g1) ACC1(2, w2, 2, g2) ACC1(2, w2, 3, g3)
#undef ACC1
        }
    }

    __syncthreads();   // all gt reads done -> reuse gt as outT[o][68]
#pragma unroll
    for (int i = 0; i < 3; ++i)
#pragma unroll
        for (int r = 0; r < 4; ++r)
            gt[(og * 3 + i) * 68 + pg * 4 + r] = acc[i][r];
    __syncthreads();

    {
        float* ob = out + (size_t)b * Cn * Ln + l0;
        for (int e4 = t; e4 < 1536; e4 += 512) {
            int o = e4 >> 4, p4 = e4 & 15;
            float4 v = *(const float4*)&gt[o * 68 + p4 * 4];
            float sc = scw[o];
            v.x *= sc; v.y *= sc; v.z *= sc; v.w *= sc;
            *(float4*)&ob[(size_t)o * Ln + p4 * 4] = v;
        }
    }
}

// ---------------------------------------------------------------------------
extern "C" void kernel_launch(void* const* d_in, const int* in_sizes, int n_in,
                              void* d_out, int out_size, void* d_ws, size_t ws_size,
                              hipStream_t stream)
{
    const float* x     = (const float*)d_in[0];
    const float* ipw   = (const float*)d_in[1];
    const float* cw    = (const float*)d_in[2];
    const float* cb    = (const float*)d_in[3];
    const float* xpw   = (const float*)d_in[4];
    const float* dtw   = (const float*)d_in[5];
    const float* dtb   = (const float*)d_in[6];
    const float* Alogs = (const float*)d_in[7];
    const float* Ds    = (const float*)d_in[8];
    const float* onw   = (const float*)d_in[9];
    const float* onb   = (const float*)d_in[10];
    const float* opw   = (const float*)d_in[11];
    const float* scw   = (const float*)d_in[12];
    float* out = (float*)d_out;

    // Workspace (R3/R8-proven layout, 3A + 3S):
    float* wsp = (float*)d_ws;
    size_t off = 0;
    // xc dead after k_conv -> y0 aliases it
    float* xc   = wsp + off;
    float* y0   = wsp + off; off += (size_t)Bn * Ln * Cn;         // 6.29M
    float* zs   = wsp + off; off += (size_t)Bn * Ln * Cn;         // 6.29M
    float* u    = wsp + off; off += (size_t)Bn * Ln * Cn;         // 6.29M
    // f (fp16, [b][l][k][c]) overlays u byte-exactly per position; each part1
    // block consumes its own u range into LDS (barrier) before overwriting it.
    __half* f   = (__half*)u;
    float* Pc    = wsp + off; off += (size_t)Bn * Kn * NCH * Cn;  // 0.79M
    float* Qc    = wsp + off; off += (size_t)Bn * Kn * NCH * Cn;
    float* hinit = wsp + off; off += (size_t)Bn * Kn * NCH * Cn;

    k_inproj<<<Bn * 128, 256, 0, stream>>>(x, ipw, xc, zs);
    k_conv  <<<(Bn * Ln * 24) / 256, 256, 0, stream>>>(xc, cw, cb, u);
    k_part1 <<<Bn * 512, 384, 0, stream>>>(u, xpw, dtw, dtb, Alogs, Ds,
                                           Pc, Qc, y0, f);
    k_scan2 <<<24, 1024, 0, stream>>>(Pc, Qc, hinit);
    k_merge <<<Bn * 256, 512, 0, stream>>>(y0, f, hinit, zs, onw, onb,
                                           opw, scw, out);
}